// Round 1
// baseline (178.225 us; speedup 1.0000x reference)
//
#include <hip/hip_runtime.h>

// Problem constants (match reference)
constexpr int B = 1024;
constexpr int C = 1024;
constexpr int K = 20;
constexpr int L = 2048;
constexpr int V = 80;
constexpr int TK = 3 * K;  // 60

// Output layout (flat, concatenated in return order):
//   w     : [B, V]    at offset 0            (81920)
//   kappa : [B, K]    at offset B*V          (20480)
//   phi   : [B, L+1]  at offset B*V + B*K    (2098176)

__global__ __launch_bounds__(256)
void window_fused_kernel(const float* __restrict__ x,
                         const float* __restrict__ W,
                         const float* __restrict__ bias,
                         const float* __restrict__ kappa_old,
                         const float* __restrict__ onehots,
                         const int*   __restrict__ text_lens,
                         float* __restrict__ out) {
    const int b = blockIdx.x;
    const int t = threadIdx.x;

    __shared__ float lds_x[C];          // 4 KB
    __shared__ float lds_phi[L + 1];    // 8.2 KB
    __shared__ float lds_abk[TK];       // alpha[0:20], beta[20:40], kappa[40:60]
    __shared__ float lds_w[V];          // 320 B

    // ---- Phase A: stage x[b,:] into LDS (coalesced float4) ----
    {
        const float4* xrow = reinterpret_cast<const float4*>(x + (size_t)b * C);
        reinterpret_cast<float4*>(lds_x)[t] = xrow[t];   // 256 * 4 = 1024 floats
    }
    if (t < V) lds_w[t] = 0.0f;
    __syncthreads();

    // ---- Phase B: params = exp(x@W + b); alpha/beta/kappa ----
    {
        const int g   = t >> 2;   // column group 0..63 (use 0..59)
        const int sub = t & 3;    // 4 lanes per column split the K=1024 reduction
        float acc = 0.0f;
        if (g < TK) {
            const float* Wg = W + g;
            #pragma unroll 4
            for (int i = 0; i < C / 4; ++i) {
                const int c = sub + 4 * i;
                acc += lds_x[c] * Wg[c * TK];
            }
        }
        // reduce the 4 partials within each quad (quads never cross a wave)
        acc += __shfl_xor(acc, 1);
        acc += __shfl_xor(acc, 2);
        if (sub == 0 && g < TK) {
            const float p = __expf(acc + bias[g]);
            if (g >= 2 * K) {                        // pre_kappa part
                const int k = g - 2 * K;
                const float kap = kappa_old[(size_t)b * K + k] + p;
                lds_abk[g] = kap;
                out[(size_t)B * V + (size_t)b * K + k] = kap;   // kappa output
            } else {
                lds_abk[g] = p;                      // alpha or beta
            }
        }
    }
    __syncthreads();

    // ---- Phase C: phi[l] = scale * sum_k alpha_k * exp(-beta_k*(kappa_k-l)^2) ----
    {
        const float scale = (float)L / (float)text_lens[b];
        float* out_phi = out + (size_t)B * V + (size_t)B * K + (size_t)b * (L + 1);
        for (int l = t; l <= L; l += 256) {
            const float fl = (float)l;
            float s = 0.0f;
            #pragma unroll
            for (int k = 0; k < K; ++k) {
                const float d = lds_abk[2 * K + k] - fl;   // kappa_k - l
                s += lds_abk[k] * __expf(-lds_abk[K + k] * d * d);
            }
            s *= scale;
            lds_phi[l] = s;
            out_phi[l] = s;
        }
    }
    __syncthreads();

    // ---- Phase D: w[v] = sum_{l<L} phi[l] * onehots[b,l,v]  (stream 640 KB) ----
    {
        const float4* oh = reinterpret_cast<const float4*>(onehots + (size_t)b * L * V);
        const int nchunk = L * V / 4;  // 40960 float4 chunks; 80 % 4 == 0 so no row-crossing
        for (int i = t; i < nchunk; i += 256) {
            const float4 v = oh[i];
            const int l  = i / 20;          // (4*i) / 80
            const int v0 = (i % 20) * 4;    // (4*i) % 80
            const float ph = lds_phi[l];
            // one-hot rows: ~1/80 density -> ~8 atomics per thread total
            if (v.x != 0.0f) atomicAdd(&lds_w[v0 + 0], ph * v.x);
            if (v.y != 0.0f) atomicAdd(&lds_w[v0 + 1], ph * v.y);
            if (v.z != 0.0f) atomicAdd(&lds_w[v0 + 2], ph * v.z);
            if (v.w != 0.0f) atomicAdd(&lds_w[v0 + 3], ph * v.w);
        }
    }
    __syncthreads();

    if (t < V) out[(size_t)b * V + t] = lds_w[t];
}

extern "C" void kernel_launch(void* const* d_in, const int* in_sizes, int n_in,
                              void* d_out, int out_size, void* d_ws, size_t ws_size,
                              hipStream_t stream) {
    const float* x         = (const float*)d_in[0];
    const float* W         = (const float*)d_in[1];
    const float* bias      = (const float*)d_in[2];
    const float* kappa_old = (const float*)d_in[3];
    const float* onehots   = (const float*)d_in[4];
    const int*   text_lens = (const int*)d_in[5];
    float* out = (float*)d_out;

    window_fused_kernel<<<B, 256, 0, stream>>>(x, W, bias, kappa_old,
                                               onehots, text_lens, out);
}

// Round 2
// 159.287 us; speedup vs baseline: 1.1189x; 1.1189x over previous
//
#include <hip/hip_runtime.h>

// Problem constants (match reference)
constexpr int B = 1024;
constexpr int C = 1024;
constexpr int K = 20;
constexpr int L = 2048;
constexpr int V = 80;
constexpr int TK = 3 * K;  // 60

// Output layout (flat, concatenated in return order):
//   w     : [B, V]    at offset 0
//   kappa : [B, K]    at offset B*V
//   phi   : [B, L+1]  at offset B*V + B*K

__global__ __launch_bounds__(256)
void window_fused_kernel(const float* __restrict__ x,
                         const float* __restrict__ W,
                         const float* __restrict__ bias,
                         const float* __restrict__ kappa_old,
                         const float* __restrict__ onehots,
                         const int*   __restrict__ text_lens,
                         float* __restrict__ out) {
    const int b = blockIdx.x;
    const int t = threadIdx.x;

    __shared__ float lds_x[C];          // 4 KB
    __shared__ float lds_phi[L + 1];    // 8.2 KB
    __shared__ float lds_abk[TK];       // alpha[0:20], beta[20:40], kappa[40:60]
    __shared__ float lds_w[V];          // 320 B

    const float4* oh = reinterpret_cast<const float4*>(onehots + (size_t)b * L * V);

    // ---- Early prefetch: first two streaming batches (8 x 16B/lane in flight
    //      while phases A-C run) ----
    float4 bufA0 = oh[t];        float4 bufA1 = oh[t + 256];
    float4 bufA2 = oh[t + 512];  float4 bufA3 = oh[t + 768];
    float4 bufB0 = oh[t + 1024]; float4 bufB1 = oh[t + 1280];
    float4 bufB2 = oh[t + 1536]; float4 bufB3 = oh[t + 1792];

    // ---- Phase A: stage x[b,:] into LDS (coalesced float4) ----
    reinterpret_cast<float4*>(lds_x)[t] =
        reinterpret_cast<const float4*>(x + (size_t)b * C)[t];
    if (t < V) lds_w[t] = 0.0f;
    __syncthreads();

    // ---- Phase B: params = exp(x@W + b); alpha/beta/kappa ----
    {
        const int g   = t >> 2;   // column 0..63 (use 0..59)
        const int sub = t & 3;    // 4 lanes split the C=1024 reduction
        float acc = 0.0f;
        if (g < TK) {
            const float* Wg = W + g;
            #pragma unroll 8
            for (int i = 0; i < C / 4; ++i) {
                const int c = sub + 4 * i;
                acc += lds_x[c] * Wg[c * TK];
            }
        }
        acc += __shfl_xor(acc, 1);
        acc += __shfl_xor(acc, 2);
        if (sub == 0 && g < TK) {
            const float p = __expf(acc + bias[g]);
            if (g >= 2 * K) {
                const int k = g - 2 * K;
                const float kap = kappa_old[(size_t)b * K + k] + p;
                lds_abk[g] = kap;
                out[(size_t)B * V + (size_t)b * K + k] = kap;
            } else {
                lds_abk[g] = p;
            }
        }
    }
    __syncthreads();

    // ---- Phase C: phi[l]; k-outer so alpha/beta/kappa stay in registers ----
    {
        float s[8];
        #pragma unroll
        for (int j = 0; j < 8; ++j) s[j] = 0.0f;
        #pragma unroll
        for (int k = 0; k < K; ++k) {
            const float a  = lds_abk[k];
            const float be = lds_abk[K + k];
            const float kp = lds_abk[2 * K + k];
            #pragma unroll
            for (int j = 0; j < 8; ++j) {
                const float d = kp - (float)(t + (j << 8));
                s[j] += a * __expf(-be * d * d);
            }
        }
        const float scale = 2048.0f / (float)text_lens[b];
        float* out_phi = out + (size_t)B * V + (size_t)B * K + (size_t)b * (L + 1);
        #pragma unroll
        for (int j = 0; j < 8; ++j) {
            const int l = t + (j << 8);
            const float v = s[j] * scale;
            lds_phi[l] = v;       // l in [0,2048); phi[2048] unused by Phase D
            out_phi[l] = v;
        }
        if (t == 0) {  // l = 2048 tail element (output only)
            float sv = 0.0f;
            #pragma unroll
            for (int k = 0; k < K; ++k) {
                const float d = lds_abk[2 * K + k] - 2048.0f;
                sv += lds_abk[k] * __expf(-lds_abk[K + k] * d * d);
            }
            out_phi[L] = sv * scale;
        }
    }
    __syncthreads();

    // ---- Phase D: w[v] += phi[l] * onehots[b,l,v], software-pipelined ----
    {
        #define PROC(vv, ii) {                                        \
            const int i_ = (ii);                                      \
            const float ph = lds_phi[i_ / 20];                        \
            const int v0 = (i_ % 20) * 4;                             \
            if (vv.x != 0.0f) atomicAdd(&lds_w[v0 + 0], ph * vv.x);   \
            if (vv.y != 0.0f) atomicAdd(&lds_w[v0 + 1], ph * vv.y);   \
            if (vv.z != 0.0f) atomicAdd(&lds_w[v0 + 2], ph * vv.z);   \
            if (vv.w != 0.0f) atomicAdd(&lds_w[v0 + 3], ph * vv.w); }

        // 160 float4 chunks per thread = 40 batches of 4, A/B double-buffered
        #pragma unroll 1
        for (int batch = 0; batch < 40; batch += 2) {
            const int ia = t + (batch << 10);
            PROC(bufA0, ia);       PROC(bufA1, ia + 256);
            PROC(bufA2, ia + 512); PROC(bufA3, ia + 768);
            if (batch + 2 < 40) {
                const int na = t + ((batch + 2) << 10);
                bufA0 = oh[na];        bufA1 = oh[na + 256];
                bufA2 = oh[na + 512];  bufA3 = oh[na + 768];
            }
            const int ib = ia + 1024;
            PROC(bufB0, ib);       PROC(bufB1, ib + 256);
            PROC(bufB2, ib + 512); PROC(bufB3, ib + 768);
            if (batch + 3 < 40) {
                const int nb = t + ((batch + 3) << 10);
                bufB0 = oh[nb];        bufB1 = oh[nb + 256];
                bufB2 = oh[nb + 512];  bufB3 = oh[nb + 768];
            }
        }
        #undef PROC
    }
    __syncthreads();

    if (t < V) out[(size_t)b * V + t] = lds_w[t];
}

extern "C" void kernel_launch(void* const* d_in, const int* in_sizes, int n_in,
                              void* d_out, int out_size, void* d_ws, size_t ws_size,
                              hipStream_t stream) {
    const float* x         = (const float*)d_in[0];
    const float* W         = (const float*)d_in[1];
    const float* bias      = (const float*)d_in[2];
    const float* kappa_old = (const float*)d_in[3];
    const float* onehots   = (const float*)d_in[4];
    const int*   text_lens = (const int*)d_in[5];
    float* out = (float*)d_out;

    window_fused_kernel<<<B, 256, 0, stream>>>(x, W, bias, kappa_old,
                                               onehots, text_lens, out);
}